// Round 4
// baseline (221.978 us; speedup 1.0000x reference)
//
#include <hip/hip_runtime.h>
#include <hip/hip_bf16.h>
#include <math.h>

// ws layout (float slots)
#define OFF_XH   0UL         // bf16 x  (bh, l, 128)
#define OFF_XT   1572864UL   // bf16 x^T (bh, 128, l) token-paired u32
#define OFF_SQ   4718592UL   // fp32 per-(bh,l) sumsq          (24576)
#define OFF_PART 4767744UL   // fp32 partials: [0..191] V-sum (bh:S1,S2); [192..575] dist (bh,jh:D1,D2)
#define OFF_ACC  4780056UL   // 336
#define OFF_CTR  4780392UL   // 1 uint (k456 completion counter)
#define OFF_FCWB 4780396UL   // bf16 fcW cast, 21*768 (8064 u16)

typedef __attribute__((ext_vector_type(8))) __bf16 bf16x8;
typedef __attribute__((ext_vector_type(4))) float f32x4;
typedef __attribute__((ext_vector_type(8))) unsigned short u16x8;

// ---------------- K12: gather -> LDS tile (+xh, xT, sq) + dist/V-BN block partials ----------------
__global__ __launch_bounds__(512) void k12_fused(const int* __restrict__ tids,
    const float* __restrict__ TF, const float* __restrict__ DF,
    const float* __restrict__ emb, unsigned short* __restrict__ xh,
    unsigned short* __restrict__ xT, float* __restrict__ sq,
    float* __restrict__ part, const float* __restrict__ fcW,
    unsigned short* __restrict__ fcWb, float* __restrict__ acc,
    unsigned int* __restrict__ ctr) {
  int jh = blockIdx.x, bh = blockIdx.y;
  int b = bh / 6, h = bh % 6;
  int tid = threadIdx.x;
  __shared__ unsigned short tile[32768];   // 64 KiB
  __shared__ float swd1[8], swd2[8], swv1[8], swv2[8];
  if (jh == 1) {                           // fcW -> bf16 cast, partitioned over 96 blocks
    if (tid < 168) {
      int idx = bh * 168 + tid;
      fcWb[idx] = __bfloat16_as_ushort(__float2bfloat16(fcW[idx]));
    }
  } else if (bh == 0) {                    // zero acc + k456 counter (1 launch ahead)
    if (tid < 336) acc[tid] = 0.0f;
    if (tid == 336) *ctr = 0u;
  }
  int sub = tid & 7, row0 = tid >> 3;      // 8 threads per token row
  int c16 = sub * 16;
  float ts1 = 0.0f, ts2 = 0.0f;            // per-thread V-sum partials
#pragma unroll
  for (int p = 0; p < 4; ++p) {
    int r = p * 64 + row0;
    int tok = b * 256 + r;
    int tv = tids[tok];
    float wgt = fminf(TF[tok], 20.0f) * log1pf(1.0f / DF[tok]);
    const float* er = emb + (size_t)tv * 768 + h * 128 + c16;
    float4 e0 = *(const float4*)er;
    float4 e1 = *(const float4*)(er + 4);
    float4 e2 = *(const float4*)(er + 8);
    float4 e3 = *(const float4*)(er + 12);
    float f[16] = {e0.x, e0.y, e0.z, e0.w, e1.x, e1.y, e1.z, e1.w,
                   e2.x, e2.y, e2.z, e2.w, e3.x, e3.y, e3.z, e3.w};
    u16x8 pk0, pk1;
    float s1 = 0.0f, s2 = 0.0f;
#pragma unroll
    for (int e = 0; e < 8; ++e) {
      __hip_bfloat16 hb = __float2bfloat16(f[e] * wgt);
      float g = __bfloat162float(hb);
      s1 += g; s2 += g * g;
      pk0[e] = __bfloat16_as_ushort(hb);
    }
#pragma unroll
    for (int e = 0; e < 8; ++e) {
      __hip_bfloat16 hb = __float2bfloat16(f[8 + e] * wgt);
      float g = __bfloat162float(hb);
      s1 += g; s2 += g * g;
      pk1[e] = __bfloat16_as_ushort(hb);
    }
    ts1 += s1; ts2 += s2;
    int rx = r & 7;
    *(u16x8*)&tile[r * 128 + (((sub * 2    ) ^ rx) * 8)] = pk0;
    *(u16x8*)&tile[r * 128 + (((sub * 2 + 1) ^ rx) * 8)] = pk1;
    if (jh == 0) {   // linear xh for k456
      unsigned short* xo = xh + ((size_t)bh * 256 + r) * 128 + c16;
      *(u16x8*)xo = pk0;
      *(u16x8*)(xo + 8) = pk1;
    }
    s2 += __shfl_down(s2, 4); s2 += __shfl_down(s2, 2); s2 += __shfl_down(s2, 1);
    if (sub == 0)
      sq[(size_t)bh * 256 + r] = s2;       // both jh blocks write identical values (benign)
  }
  __syncthreads();
  // jh==1 block emits the channel-major transpose xT (token-paired u32) from LDS
  if (jh == 1) {
    int ch = tid & 127, q = tid >> 7;          // 4 token-quarters
    int cc = ch >> 3, cs = ch & 7;
    unsigned int* xo = (unsigned int*)xT + ((size_t)bh * 128 + ch) * 128 + q * 32;
#pragma unroll
    for (int g = 0; g < 8; ++g) {
      unsigned int tmp[4];
#pragma unroll
      for (int k = 0; k < 4; ++k) {
        int t0 = q * 64 + (g * 4 + k) * 2;
        unsigned int lo = tile[ t0      * 128 + ((cc ^ ( t0      & 7)) * 8) + cs];
        unsigned int hi = tile[(t0 + 1) * 128 + ((cc ^ ((t0 + 1) & 7)) * 8) + cs];
        tmp[k] = lo | (hi << 16);
      }
      uint4 vv; vv.x = tmp[0]; vv.y = tmp[1]; vv.z = tmp[2]; vv.w = tmp[3];
      *(uint4*)(xo + g * 4) = vv;
    }
  }
  // dist-BN partials: wave w -> i-tiles {2w,2w+1}, cols [128*jh, 128*jh+128)
  int w = tid >> 6, lane = tid & 63, quad = lane >> 4, l16 = lane & 15;
  const float* sqh = sq + (size_t)bh * 256;
  int it0 = w * 2;
  bf16x8 a2[2][4];
  float si2[2][4];
#pragma unroll
  for (int ith = 0; ith < 2; ++ith) {
    int ar = (it0 + ith) * 16 + l16, arx = ar & 7;
#pragma unroll
    for (int k0 = 0; k0 < 4; ++k0)
      a2[ith][k0] = *(const bf16x8*)&tile[ar * 128 + (((k0 * 4 + quad) ^ arx) * 8)];
#pragma unroll
    for (int r = 0; r < 4; ++r)
      si2[ith][r] = sqh[(it0 + ith) * 16 + quad * 4 + r];
  }
  float ls1 = 0.0f, ls2 = 0.0f;
#pragma unroll
  for (int jt = 0; jt < 8; ++jt) {
    int jr = jh * 128 + jt * 16 + l16, jrx = jr & 7;
    bf16x8 bfr[4];
#pragma unroll
    for (int k0 = 0; k0 < 4; ++k0)
      bfr[k0] = *(const bf16x8*)&tile[jr * 128 + (((k0 * 4 + quad) ^ jrx) * 8)];
    f32x4 acc0 = {0.0f, 0.0f, 0.0f, 0.0f}, acc1 = {0.0f, 0.0f, 0.0f, 0.0f};
#pragma unroll
    for (int k0 = 0; k0 < 4; ++k0) {
      acc0 = __builtin_amdgcn_mfma_f32_16x16x32_bf16(a2[0][k0], bfr[k0], acc0, 0, 0, 0);
      acc1 = __builtin_amdgcn_mfma_f32_16x16x32_bf16(a2[1][k0], bfr[k0], acc1, 0, 0, 0);
    }
    float sj = sqh[jr];
#pragma unroll
    for (int r = 0; r < 4; ++r) {
      float cv0 = sqrtf(fmaxf(si2[0][r] + sj - 2.0f * acc0[r], 1e-12f));
      float cv1 = sqrtf(fmaxf(si2[1][r] + sj - 2.0f * acc1[r], 1e-12f));
      ls1 += cv0 + cv1;
      ls2 += cv0 * cv0 + cv1 * cv1;
    }
  }
#pragma unroll
  for (int off = 32; off >= 1; off >>= 1) {
    ls1 += __shfl_down(ls1, off);
    ls2 += __shfl_down(ls2, off);
    ts1 += __shfl_down(ts1, off);
    ts2 += __shfl_down(ts2, off);
  }
  if (lane == 0) { swd1[w] = ls1; swd2[w] = ls2; swv1[w] = ts1; swv2[w] = ts2; }
  __syncthreads();
  if (tid == 0) {
    float d1 = 0.0f, d2 = 0.0f, v1 = 0.0f, v2 = 0.0f;
#pragma unroll
    for (int i = 0; i < 8; ++i) { d1 += swd1[i]; d2 += swd2[i]; v1 += swv1[i]; v2 += swv2[i]; }
    part[192 + (bh * 2 + jh) * 2 + 0] = d1;
    part[192 + (bh * 2 + jh) * 2 + 1] = d2;
    if (jh == 0) { part[bh * 2] = v1; part[bh * 2 + 1] = v2; }
  }
}

// ---------------- K456: per (b, 16-token tile): all 6 heads dist+softmax+AV into LDS vc,
// then fc matmul + 21-softmax + per-b accumulate + last-block final 20-softmax. ----------------
// 256 blocks (1/CU), 512 threads (8 waves). XCD-pinned by b (2 b per XCD -> xh/xT L2-resident).
__global__ __launch_bounds__(512) void k456_fused(const unsigned short* __restrict__ xh,
    const unsigned short* __restrict__ xT, const int* __restrict__ tids,
    const float* __restrict__ sq, const float* __restrict__ part,
    const unsigned short* __restrict__ fcWb, const float* __restrict__ fcb,
    float* __restrict__ acc, unsigned int* __restrict__ ctr, float* __restrict__ out) {
  int bid = blockIdx.x;
  int xcd = bid & 7, idx = bid >> 3;       // 32 blocks per XCD
  int b = xcd * 2 + (idx >> 4);            // 2 b per XCD
  int p = idx & 15;
  int tid = threadIdx.x, w = tid >> 6, lane = tid & 63;
  int quad = lane >> 4, l16 = lane & 15;
  int I = p * 16;
  __shared__ float svld[256];
  __shared__ float ssqall[1536];           // sq for all 6 heads of this b
  __shared__ unsigned short cot[16][264];  // softmaxed co tile (reused per head)
  __shared__ float smax[16][8];
  __shared__ float ssum[16][8];
  __shared__ float sstat[24];              // per h: m, rsc, mv, rvs
  __shared__ unsigned short vct[16][776];  // 16 tokens x 768 vc (bf16), +8 pad (2-way banks)
  __shared__ float sacc[16][22];           // fc logits reduce
  __shared__ float facc[21];               // class-prob reduce over 16 tokens
  __shared__ unsigned int sdone;
  if (tid < 256) svld[tid] = (tids[b * 256 + tid] != 0) ? 1.0f : 0.0f;
  for (int i = tid; i < 1536; i += 512) ssqall[i] = sq[(size_t)b * 1536 + i];
  if (tid < 352) ((float*)sacc)[tid] = 0.0f;
  if (tid >= 352 && tid < 373) facc[tid - 352] = 0.0f;
  if (w < 6) {                             // wave w finalizes BN stats for h=w
    int h = w;
    float c1 = 0.0f, c2 = 0.0f;
    if (lane < 32) {
      int bb = lane >> 1, jj = lane & 1;
      c1 = part[192 + ((bb * 6 + h) * 2 + jj) * 2 + 0];
      c2 = part[192 + ((bb * 6 + h) * 2 + jj) * 2 + 1];
    }
#pragma unroll
    for (int off = 16; off >= 1; off >>= 1) {
      c1 += __shfl_down(c1, off);
      c2 += __shfl_down(c2, off);
    }
    float v1 = 0.0f, v2 = 0.0f;
    if (lane < 16) {
      v1 = part[(lane * 6 + h) * 2 + 0];
      v2 = part[(lane * 6 + h) * 2 + 1];
    }
#pragma unroll
    for (int off = 8; off >= 1; off >>= 1) {
      v1 += __shfl_down(v1, off);
      v2 += __shfl_down(v2, off);
    }
    if (lane == 0) {
      float mean = c1 / 1048576.0f;                    // B*L*L
      float var = c2 / 1048576.0f - mean * mean;
      sstat[h * 4 + 0] = mean;
      sstat[h * 4 + 1] = rsqrtf(var + 1e-5f);
      float mv = v1 / 524288.0f;                       // B*L*dh
      float vv = v2 / 524288.0f - mv * mv;
      sstat[h * 4 + 2] = mv;
      sstat[h * 4 + 3] = rsqrtf(vv + 1e-5f);
    }
  }
  __syncthreads();
  for (int h = 0; h < 6; ++h) {
    int bh = b * 6 + h;
    const __bf16* xb = (const __bf16*)xh + (size_t)bh * 256 * 128;
    bf16x8 a[4];
#pragma unroll
    for (int k0 = 0; k0 < 4; ++k0)
      a[k0] = *(const bf16x8*)(xb + (size_t)(I + l16) * 128 + k0 * 32 + quad * 8);
    float m = sstat[h * 4 + 0], rsc = sstat[h * 4 + 1];
    float rv[4], si[4];
#pragma unroll
    for (int r = 0; r < 4; ++r) {
      rv[r] = svld[I + quad * 4 + r];
      si[r] = ssqall[h * 256 + I + quad * 4 + r];
    }
    float y[2][4];
#pragma unroll
    for (int tl = 0; tl < 2; ++tl) {
      int t = w * 2 + tl;
      f32x4 accd = {0.0f, 0.0f, 0.0f, 0.0f};
#pragma unroll
      for (int k0 = 0; k0 < 4; ++k0) {
        bf16x8 bfr = *(const bf16x8*)(xb + (size_t)(t * 16 + l16) * 128 + k0 * 32 + quad * 8);
        accd = __builtin_amdgcn_mfma_f32_16x16x32_bf16(a[k0], bfr, accd, 0, 0, 0);
      }
      float sj = ssqall[h * 256 + t * 16 + l16];
      float cvld = svld[t * 16 + l16];
#pragma unroll
      for (int r = 0; r < 4; ++r) {
        float cv = sqrtf(fmaxf(si[r] + sj - 2.0f * accd[r], 1e-12f));
        float yv = (cv - m) * rsc;
        yv = yv >= 0.0f ? yv : 9.0f * yv;
        y[tl][r] = yv * rv[r] * cvld;
      }
    }
#pragma unroll
    for (int r = 0; r < 4; ++r) {
      float mx = fmaxf(y[0][r], y[1][r]);
#pragma unroll
      for (int off = 1; off <= 8; off <<= 1) mx = fmaxf(mx, __shfl_xor(mx, off));
      if (l16 == 0) smax[quad * 4 + r][w] = mx;
    }
    __syncthreads();
    float gmx[4];
#pragma unroll
    for (int r = 0; r < 4; ++r) {
      int row = quad * 4 + r;
      float g0 = fmaxf(fmaxf(smax[row][0], smax[row][1]), fmaxf(smax[row][2], smax[row][3]));
      float g1 = fmaxf(fmaxf(smax[row][4], smax[row][5]), fmaxf(smax[row][6], smax[row][7]));
      gmx[r] = fmaxf(g0, g1);
      float s = 0.0f;
#pragma unroll
      for (int tl = 0; tl < 2; ++tl) { y[tl][r] = expf(y[tl][r] - gmx[r]); s += y[tl][r]; }
#pragma unroll
      for (int off = 1; off <= 8; off <<= 1) s += __shfl_xor(s, off);
      if (l16 == 0) ssum[row][w] = s;
    }
    __syncthreads();
#pragma unroll
    for (int r = 0; r < 4; ++r) {
      int row = quad * 4 + r;
      float gs = (ssum[row][0] + ssum[row][1] + ssum[row][2] + ssum[row][3])
               + (ssum[row][4] + ssum[row][5] + ssum[row][6] + ssum[row][7]);
      float inv = 1.0f / gs;
#pragma unroll
      for (int tl = 0; tl < 2; ++tl)
        cot[row][w * 32 + tl * 16 + l16] =
            __bfloat16_as_ushort(__float2bfloat16(y[tl][r] * inv));
    }
    __syncthreads();
    // AV: wave w -> ch-tile w (16 channels); output into LDS vc tile
    bf16x8 a2[8];
#pragma unroll
    for (int k0 = 0; k0 < 8; ++k0)
      a2[k0] = *(const bf16x8*)&cot[l16][k0 * 32 + quad * 8];
    const __bf16* xbT = (const __bf16*)xT + (size_t)bh * 128 * 256;
    float mv = sstat[h * 4 + 2], rvs = sstat[h * 4 + 3];
    float rm = rvs * mv;
    int ch = w * 16 + l16;
    const __bf16* brow = xbT + (size_t)ch * 256;
    f32x4 vacc = {0.0f, 0.0f, 0.0f, 0.0f};
#pragma unroll
    for (int k0 = 0; k0 < 8; ++k0) {
      bf16x8 bfr = *(const bf16x8*)(brow + k0 * 32 + quad * 8);
      vacc = __builtin_amdgcn_mfma_f32_16x16x32_bf16(a2[k0], bfr, vacc, 0, 0, 0);
    }
#pragma unroll
    for (int r = 0; r < 4; ++r) {
      float ov = rvs * vacc[r] - rm;
      vct[quad * 4 + r][h * 128 + ch] = __bfloat16_as_ushort(__float2bfloat16(ov));
    }
    __syncthreads();   // guards cot/smax/ssum reuse next head; last iter guards vct for fc
  }
  // fc phase: wave w handles k-steps {3w, 3w+1, 3w+2} of 24; split-K reduce via LDS atomics
  int c1c = (l16 < 5) ? (16 + l16) : 20;
  const __bf16* w0 = (const __bf16*)fcWb + (size_t)l16 * 768;
  const __bf16* w1 = (const __bf16*)fcWb + (size_t)c1c * 768;
  f32x4 ac0 = {0.0f, 0.0f, 0.0f, 0.0f}, ac1 = {0.0f, 0.0f, 0.0f, 0.0f};
#pragma unroll
  for (int s = 0; s < 3; ++s) {
    int ko = (w * 3 + s) * 32 + quad * 8;
    bf16x8 af = *(const bf16x8*)&vct[l16][ko];
    bf16x8 b0 = *(const bf16x8*)(w0 + ko);
    bf16x8 b1 = *(const bf16x8*)(w1 + ko);
    ac0 = __builtin_amdgcn_mfma_f32_16x16x32_bf16(af, b0, ac0, 0, 0, 0);
    ac1 = __builtin_amdgcn_mfma_f32_16x16x32_bf16(af, b1, ac1, 0, 0, 0);
  }
#pragma unroll
  for (int r = 0; r < 4; ++r) {
    atomicAdd(&sacc[quad * 4 + r][l16], ac0[r]);
    if (l16 < 5) atomicAdd(&sacc[quad * 4 + r][16 + l16], ac1[r]);
  }
  __syncthreads();
  // per-token softmax over 21 classes, then class-reduce over the 16 tokens
  if (tid < 16) {
    int row = tid;
    float lg[21], mx = -1e30f;
#pragma unroll
    for (int c = 0; c < 21; ++c) { lg[c] = sacc[row][c] + fcb[c]; mx = fmaxf(mx, lg[c]); }
    float s = 0.0f;
#pragma unroll
    for (int c = 0; c < 21; ++c) { lg[c] = expf(lg[c] - mx); s += lg[c]; }
    float inv = 1.0f / s;
#pragma unroll
    for (int c = 0; c < 21; ++c) atomicAdd(&facc[c], lg[c] * inv);
  }
  __syncthreads();
  if (tid < 21) atomicAdd(&acc[b * 21 + tid], facc[tid]);
  __syncthreads();   // barrier drains vmcnt: this block's atomics are globally performed
  if (tid == 0) {
    __threadfence();
    sdone = atomicAdd(ctr, 1u);
  }
  __syncthreads();
  if (sdone == 255u && tid < 16) {
    float v[20];
    float mx = -1e30f;
#pragma unroll
    for (int c = 0; c < 20; ++c) {
      v[c] = atomicAdd(&acc[tid * 21 + c], 0.0f);   // coherent read (XCD-safe)
      mx = fmaxf(mx, v[c]);
    }
    float s = 0.0f;
#pragma unroll
    for (int c = 0; c < 20; ++c) { v[c] = expf(v[c] - mx); s += v[c]; }
    float inv = 1.0f / s;
#pragma unroll
    for (int c = 0; c < 20; ++c) out[tid * 20 + c] = v[c] * inv;
  }
}

extern "C" void kernel_launch(void* const* d_in, const int* in_sizes, int n_in,
                              void* d_out, int out_size, void* d_ws, size_t ws_size,
                              hipStream_t stream) {
  const int*   tids = (const int*)d_in[0];
  const float* TF   = (const float*)d_in[1];
  const float* DF   = (const float*)d_in[2];
  const float* emb  = (const float*)d_in[3];
  const float* fcW  = (const float*)d_in[4];
  const float* fcb  = (const float*)d_in[5];
  // d_in[6]=weiW, d_in[7]=weib: dead code (cw branch is provably all-ones)
  float* out = (float*)d_out;
  float* ws  = (float*)d_ws;
  unsigned short* xh   = (unsigned short*)(ws + OFF_XH);
  unsigned short* xT   = (unsigned short*)(ws + OFF_XT);
  unsigned short* fcWb = (unsigned short*)(ws + OFF_FCWB);
  float* sq    = ws + OFF_SQ;
  float* part  = ws + OFF_PART;
  float* acc   = ws + OFF_ACC;
  unsigned int* ctr = (unsigned int*)(ws + OFF_CTR);

  k12_fused<<<dim3(2, 96), 512, 0, stream>>>(tids, TF, DF, emb, xh, xT, sq, part,
                                             fcW, fcWb, acc, ctr);
  k456_fused<<<256, 512, 0, stream>>>(xh, xT, tids, sq, part, fcWb, fcb, acc, ctr, out);
}

// Round 5
// 191.776 us; speedup vs baseline: 1.1575x; 1.1575x over previous
//
#include <hip/hip_runtime.h>
#include <hip/hip_bf16.h>
#include <math.h>

// ws layout (float slots)
#define OFF_XH   0UL         // bf16 x  (bh, l, 128)
#define OFF_XT   1572864UL   // bf16 x^T (bh, 128, l) token-paired u32
#define OFF_VC   3145728UL   // bf16 vc (b, l, 768)
#define OFF_SQ   4718592UL   // fp32 per-(bh,l) sumsq          (24576)
#define OFF_PART 4767744UL   // fp32 partials: [0..191] V-sum (bh:S1,S2); [192..959] dist (bh,jq:D1,D2)
#define OFF_ACC  4780056UL   // 336
#define OFF_CTR  4780392UL   // 1 uint (k5b6 completion counter)
#define OFF_FCWB 4780396UL   // bf16 fcW cast, 21*768 (8064 u16)

typedef __attribute__((ext_vector_type(8))) __bf16 bf16x8;
typedef __attribute__((ext_vector_type(4))) float f32x4;
typedef __attribute__((ext_vector_type(8))) unsigned short u16x8;

// ---------------- K12: gather -> LDS tile (+xh, xT, sq) + dist/V-BN block partials ----------------
// 1D grid 384, XCD-pinned: xcd=bid&7, bh=xcd*12+idx%12, jq=idx/12 (4 col-quarters per bh).
// 2 blocks/CU resident (65.7KB LDS) -> ~12 waves/CU vs old 6; dist work per block halved vs jh-split.
__global__ __launch_bounds__(512) void k12_fused(const int* __restrict__ tids,
    const float* __restrict__ TF, const float* __restrict__ DF,
    const float* __restrict__ emb, unsigned short* __restrict__ xh,
    unsigned short* __restrict__ xT, float* __restrict__ sq,
    float* __restrict__ part, const float* __restrict__ fcW,
    unsigned short* __restrict__ fcWb, float* __restrict__ acc,
    unsigned int* __restrict__ ctr) {
  int bid = blockIdx.x;
  int xcd = bid & 7, idx = bid >> 3;       // 48 blocks per XCD
  int bh = xcd * 12 + idx % 12;            // same bh->XCD map as k45 (L2 handoff)
  int jq = idx / 12;                       // 0..3: dist col-quarter
  int b = bh / 6, h = bh % 6;
  int tid = threadIdx.x;
  __shared__ unsigned short tile[32768];   // 64 KiB
  __shared__ float swd1[8], swd2[8], swv1[8], swv2[8];
  if (jq == 1) {                           // fcW -> bf16 cast, partitioned over 96 blocks
    if (tid < 168) {
      int i2 = bh * 168 + tid;
      fcWb[i2] = __bfloat16_as_ushort(__float2bfloat16(fcW[i2]));
    }
  } else if (jq == 0 && bh == 0) {         // zero acc + k5b6 counter (2 launches ahead)
    if (tid < 336) acc[tid] = 0.0f;
    if (tid == 336) *ctr = 0u;
  }
  int sub = tid & 7, row0 = tid >> 3;      // 8 threads per token row
  int c16 = sub * 16;
  float ts1 = 0.0f, ts2 = 0.0f;            // per-thread V-sum partials
#pragma unroll
  for (int p = 0; p < 4; ++p) {
    int r = p * 64 + row0;
    int tok = b * 256 + r;
    int tv = tids[tok];
    float wgt = fminf(TF[tok], 20.0f) * log1pf(1.0f / DF[tok]);
    const float* er = emb + (size_t)tv * 768 + h * 128 + c16;
    float4 e0 = *(const float4*)er;
    float4 e1 = *(const float4*)(er + 4);
    float4 e2 = *(const float4*)(er + 8);
    float4 e3 = *(const float4*)(er + 12);
    float f[16] = {e0.x, e0.y, e0.z, e0.w, e1.x, e1.y, e1.z, e1.w,
                   e2.x, e2.y, e2.z, e2.w, e3.x, e3.y, e3.z, e3.w};
    u16x8 pk0, pk1;
    float s1 = 0.0f, s2 = 0.0f;
#pragma unroll
    for (int e = 0; e < 8; ++e) {
      __hip_bfloat16 hb = __float2bfloat16(f[e] * wgt);
      float g = __bfloat162float(hb);
      s1 += g; s2 += g * g;
      pk0[e] = __bfloat16_as_ushort(hb);
    }
#pragma unroll
    for (int e = 0; e < 8; ++e) {
      __hip_bfloat16 hb = __float2bfloat16(f[8 + e] * wgt);
      float g = __bfloat162float(hb);
      s1 += g; s2 += g * g;
      pk1[e] = __bfloat16_as_ushort(hb);
    }
    ts1 += s1; ts2 += s2;
    int rx = r & 7;
    *(u16x8*)&tile[r * 128 + (((sub * 2    ) ^ rx) * 8)] = pk0;
    *(u16x8*)&tile[r * 128 + (((sub * 2 + 1) ^ rx) * 8)] = pk1;
    if (jq == 0) {   // linear xh for k45
      unsigned short* xo = xh + ((size_t)bh * 256 + r) * 128 + c16;
      *(u16x8*)xo = pk0;
      *(u16x8*)(xo + 8) = pk1;
    }
    s2 += __shfl_down(s2, 4); s2 += __shfl_down(s2, 2); s2 += __shfl_down(s2, 1);
    if (sub == 0)
      sq[(size_t)bh * 256 + r] = s2;       // all 4 jq blocks write identical values (benign)
  }
  __syncthreads();
  // jq==3 block emits the channel-major transpose xT (token-paired u32) from LDS
  if (jq == 3) {
    int ch = tid & 127, q = tid >> 7;          // 4 token-quarters
    int cc = ch >> 3, cs = ch & 7;
    unsigned int* xo = (unsigned int*)xT + ((size_t)bh * 128 + ch) * 128 + q * 32;
#pragma unroll
    for (int g = 0; g < 8; ++g) {
      unsigned int tmp[4];
#pragma unroll
      for (int k = 0; k < 4; ++k) {
        int t0 = q * 64 + (g * 4 + k) * 2;
        unsigned int lo = tile[ t0      * 128 + ((cc ^ ( t0      & 7)) * 8) + cs];
        unsigned int hi = tile[(t0 + 1) * 128 + ((cc ^ ((t0 + 1) & 7)) * 8) + cs];
        tmp[k] = lo | (hi << 16);
      }
      uint4 vv; vv.x = tmp[0]; vv.y = tmp[1]; vv.z = tmp[2]; vv.w = tmp[3];
      *(uint4*)(xo + g * 4) = vv;
    }
  }
  // dist-BN partials: wave w -> i-tiles {2w,2w+1}, cols [64*jq, 64*jq+64)
  int w = tid >> 6, lane = tid & 63, quad = lane >> 4, l16 = lane & 15;
  const float* sqh = sq + (size_t)bh * 256;
  int it0 = w * 2;
  bf16x8 a2[2][4];
  float si2[2][4];
#pragma unroll
  for (int ith = 0; ith < 2; ++ith) {
    int ar = (it0 + ith) * 16 + l16, arx = ar & 7;
#pragma unroll
    for (int k0 = 0; k0 < 4; ++k0)
      a2[ith][k0] = *(const bf16x8*)&tile[ar * 128 + (((k0 * 4 + quad) ^ arx) * 8)];
#pragma unroll
    for (int r = 0; r < 4; ++r)
      si2[ith][r] = sqh[(it0 + ith) * 16 + quad * 4 + r];
  }
  float ls1 = 0.0f, ls2 = 0.0f;
#pragma unroll
  for (int jt = 0; jt < 4; ++jt) {
    int jr = jq * 64 + jt * 16 + l16, jrx = jr & 7;
    bf16x8 bfr[4];
#pragma unroll
    for (int k0 = 0; k0 < 4; ++k0)
      bfr[k0] = *(const bf16x8*)&tile[jr * 128 + (((k0 * 4 + quad) ^ jrx) * 8)];
    f32x4 acc0 = {0.0f, 0.0f, 0.0f, 0.0f}, acc1 = {0.0f, 0.0f, 0.0f, 0.0f};
#pragma unroll
    for (int k0 = 0; k0 < 4; ++k0) {
      acc0 = __builtin_amdgcn_mfma_f32_16x16x32_bf16(a2[0][k0], bfr[k0], acc0, 0, 0, 0);
      acc1 = __builtin_amdgcn_mfma_f32_16x16x32_bf16(a2[1][k0], bfr[k0], acc1, 0, 0, 0);
    }
    float sj = sqh[jr];
#pragma unroll
    for (int r = 0; r < 4; ++r) {
      float cv0 = sqrtf(fmaxf(si2[0][r] + sj - 2.0f * acc0[r], 1e-12f));
      float cv1 = sqrtf(fmaxf(si2[1][r] + sj - 2.0f * acc1[r], 1e-12f));
      ls1 += cv0 + cv1;
      ls2 += cv0 * cv0 + cv1 * cv1;
    }
  }
#pragma unroll
  for (int off = 32; off >= 1; off >>= 1) {
    ls1 += __shfl_down(ls1, off);
    ls2 += __shfl_down(ls2, off);
    ts1 += __shfl_down(ts1, off);
    ts2 += __shfl_down(ts2, off);
  }
  if (lane == 0) { swd1[w] = ls1; swd2[w] = ls2; swv1[w] = ts1; swv2[w] = ts2; }
  __syncthreads();
  if (tid == 0) {
    float d1 = 0.0f, d2 = 0.0f, v1 = 0.0f, v2 = 0.0f;
#pragma unroll
    for (int i = 0; i < 8; ++i) { d1 += swd1[i]; d2 += swd2[i]; v1 += swv1[i]; v2 += swv2[i]; }
    part[192 + (bh * 4 + jq) * 2 + 0] = d1;
    part[192 + (bh * 4 + jq) * 2 + 1] = d2;
    if (jq == 0) { part[bh * 2] = v1; part[bh * 2 + 1] = v2; }
  }
}

// ---------------- K45: stats finalize + dist+bn+leaky+mask+softmax (LDS co) + AV ----------------
// 1D grid 1536, XCD-aware: all 16 p-blocks of a bh land on the XCD that produced xh/xT(bh).
__global__ __launch_bounds__(256, 4) void k45_fused(const unsigned short* __restrict__ xh,
    const unsigned short* __restrict__ xT, const int* __restrict__ tids,
    const float* __restrict__ sq, const float* __restrict__ part,
    unsigned short* __restrict__ vc16) {
  int bid = blockIdx.x;
  int xcd = bid & 7, idx = bid >> 3;
  int bh = xcd * 12 + idx % 12;            // 96 bh / 8 XCDs = 12 each
  int p = idx / 12;
  int b = bh / 6, h = bh % 6;
  int tid = threadIdx.x, w = tid >> 6, lane = tid & 63;
  int quad = lane >> 4, l16 = lane & 15;
  int I = p * 16;
  __shared__ float svld[256];
  __shared__ float ssq[256];
  __shared__ unsigned short cot[16][264];
  __shared__ float smax[16][4];
  __shared__ float ssum[16][4];
  __shared__ float sstat[4];               // m, rsc, mv, rvs
  svld[tid] = (tids[b * 256 + tid] != 0) ? 1.0f : 0.0f;
  ssq[tid] = sq[(size_t)bh * 256 + tid];
  if (w == 0) {                            // finalize BN stats from k12 partials (this h only)
    float c1 = 0.0f, c2 = 0.0f;
    {
      int bb = lane >> 2, jj = lane & 3;   // 16 b x 4 jq = 64 lanes
      c1 = part[192 + ((bb * 6 + h) * 4 + jj) * 2 + 0];
      c2 = part[192 + ((bb * 6 + h) * 4 + jj) * 2 + 1];
    }
#pragma unroll
    for (int off = 32; off >= 1; off >>= 1) {
      c1 += __shfl_down(c1, off);
      c2 += __shfl_down(c2, off);
    }
    float v1 = 0.0f, v2 = 0.0f;
    if (lane < 16) {
      v1 = part[(lane * 6 + h) * 2 + 0];
      v2 = part[(lane * 6 + h) * 2 + 1];
    }
#pragma unroll
    for (int off = 8; off >= 1; off >>= 1) {
      v1 += __shfl_down(v1, off);
      v2 += __shfl_down(v2, off);
    }
    if (lane == 0) {
      float mean = c1 / 1048576.0f;                    // B*L*L
      float var = c2 / 1048576.0f - mean * mean;
      sstat[0] = mean;
      sstat[1] = rsqrtf(var + 1e-5f);
      float mv = v1 / 524288.0f;                       // B*L*dh
      float vv = v2 / 524288.0f - mv * mv;
      sstat[2] = mv;
      sstat[3] = rsqrtf(vv + 1e-5f);
    }
  }
  const __bf16* xb = (const __bf16*)xh + (size_t)bh * 256 * 128;
  bf16x8 a[4];
#pragma unroll
  for (int k0 = 0; k0 < 4; ++k0)
    a[k0] = *(const bf16x8*)(xb + (size_t)(I + l16) * 128 + k0 * 32 + quad * 8);
  __syncthreads();
  float m = sstat[0], rsc = sstat[1];
  float rv[4], si[4];
#pragma unroll
  for (int r = 0; r < 4; ++r) {
    rv[r] = svld[I + quad * 4 + r];
    si[r] = ssq[I + quad * 4 + r];
  }
  float y[4][4];
#pragma unroll
  for (int tl = 0; tl < 4; ++tl) {
    int t = w * 4 + tl;
    f32x4 acc = {0.0f, 0.0f, 0.0f, 0.0f};
#pragma unroll
    for (int k0 = 0; k0 < 4; ++k0) {
      bf16x8 bfr = *(const bf16x8*)(xb + (size_t)(t * 16 + l16) * 128 + k0 * 32 + quad * 8);
      acc = __builtin_amdgcn_mfma_f32_16x16x32_bf16(a[k0], bfr, acc, 0, 0, 0);
    }
    float sj = ssq[t * 16 + l16];
    float cvld = svld[t * 16 + l16];
#pragma unroll
    for (int r = 0; r < 4; ++r) {
      float cv = sqrtf(fmaxf(si[r] + sj - 2.0f * acc[r], 1e-12f));
      float yv = (cv - m) * rsc;
      yv = yv >= 0.0f ? yv : 9.0f * yv;
      y[tl][r] = yv * rv[r] * cvld;
    }
  }
#pragma unroll
  for (int r = 0; r < 4; ++r) {
    float mx = fmaxf(fmaxf(y[0][r], y[1][r]), fmaxf(y[2][r], y[3][r]));
#pragma unroll
    for (int off = 1; off <= 8; off <<= 1) mx = fmaxf(mx, __shfl_xor(mx, off));
    if (l16 == 0) smax[quad * 4 + r][w] = mx;
  }
  __syncthreads();
  float gmx[4];
#pragma unroll
  for (int r = 0; r < 4; ++r) {
    int row = quad * 4 + r;
    gmx[r] = fmaxf(fmaxf(smax[row][0], smax[row][1]), fmaxf(smax[row][2], smax[row][3]));
    float s = 0.0f;
#pragma unroll
    for (int tl = 0; tl < 4; ++tl) { y[tl][r] = expf(y[tl][r] - gmx[r]); s += y[tl][r]; }
#pragma unroll
    for (int off = 1; off <= 8; off <<= 1) s += __shfl_xor(s, off);
    if (l16 == 0) ssum[row][w] = s;
  }
  __syncthreads();
#pragma unroll
  for (int r = 0; r < 4; ++r) {
    int row = quad * 4 + r;
    float gs = ssum[row][0] + ssum[row][1] + ssum[row][2] + ssum[row][3];
    float inv = 1.0f / gs;
#pragma unroll
    for (int tl = 0; tl < 4; ++tl)
      cot[row][w * 64 + tl * 16 + l16] =
          __bfloat16_as_ushort(__float2bfloat16(y[tl][r] * inv));
  }
  __syncthreads();
  bf16x8 a2[8];
#pragma unroll
  for (int k0 = 0; k0 < 8; ++k0)
    a2[k0] = *(const bf16x8*)&cot[l16][k0 * 32 + quad * 8];
  const __bf16* xbT = (const __bf16*)xT + (size_t)bh * 128 * 256;
  float mv = sstat[2], rvs = sstat[3];
  float rm = rvs * mv;
  size_t vbase = ((size_t)(b * 256 + I + quad * 4)) * 768 + h * 128;
#pragma unroll
  for (int jl = 0; jl < 2; ++jl) {
    int ch = (w * 2 + jl) * 16 + l16;
    const __bf16* brow = xbT + (size_t)ch * 256;
    f32x4 vacc = {0.0f, 0.0f, 0.0f, 0.0f};
#pragma unroll
    for (int k0 = 0; k0 < 8; ++k0) {
      bf16x8 bfr = *(const bf16x8*)(brow + k0 * 32 + quad * 8);
      vacc = __builtin_amdgcn_mfma_f32_16x16x32_bf16(a2[k0], bfr, vacc, 0, 0, 0);
    }
#pragma unroll
    for (int r = 0; r < 4; ++r) {
      float ov = rvs * vacc[r] - rm;
      vc16[vbase + (size_t)r * 768 + ch] = __bfloat16_as_ushort(__float2bfloat16(ov));
    }
  }
}

// ---------------- K5b6: logits via MFMA + 21-softmax + accumulate + last-block final softmax ----------------
// XCD-pinned so each block reads vc(b) from the XCD whose k45 blocks produced it (L2-resident).
__global__ __launch_bounds__(256) void k5b6_lgts(const unsigned short* __restrict__ vc16,
    const unsigned short* __restrict__ fcWb, const float* __restrict__ fcb,
    float* __restrict__ acc, unsigned int* __restrict__ ctr, float* __restrict__ out) {
  int bid = blockIdx.x;
  int xcd = bid & 7, idx = bid >> 3;       // 8 blocks per XCD
  int b = xcd * 2 + (idx & 1);             // matches k45's b->XCD map
  int qa = idx >> 1;
  int tid = threadIdx.x, w = tid >> 6, lane = tid & 63;
  int quad = lane >> 4, l16 = lane & 15;
  int tok0 = b * 256 + qa * 64 + w * 16;
  int c1c = (l16 < 5) ? (16 + l16) : 20;
  const __bf16* vb = (const __bf16*)vc16;
  const __bf16* w0 = (const __bf16*)fcWb + (size_t)l16 * 768;
  const __bf16* w1 = (const __bf16*)fcWb + (size_t)c1c * 768;
  f32x4 ac0 = {0.0f, 0.0f, 0.0f, 0.0f}, ac1 = {0.0f, 0.0f, 0.0f, 0.0f};
#pragma unroll
  for (int k0 = 0; k0 < 24; ++k0) {
    int ko = k0 * 32 + quad * 8;
    bf16x8 af = *(const bf16x8*)(vb + (size_t)(tok0 + l16) * 768 + ko);
    bf16x8 b0 = *(const bf16x8*)(w0 + ko);
    bf16x8 b1 = *(const bf16x8*)(w1 + ko);
    ac0 = __builtin_amdgcn_mfma_f32_16x16x32_bf16(af, b0, ac0, 0, 0, 0);
    ac1 = __builtin_amdgcn_mfma_f32_16x16x32_bf16(af, b1, ac1, 0, 0, 0);
  }
  float bias0 = fcb[l16];
  float bias1 = (l16 < 5) ? fcb[16 + l16] : 0.0f;
  float p0s = 0.0f, p1s = 0.0f;
#pragma unroll
  for (int r = 0; r < 4; ++r) {
    float lg0 = ac0[r] + bias0;
    float lg1 = (l16 < 5) ? (ac1[r] + bias1) : -1e30f;
    float mx = fmaxf(lg0, lg1);
#pragma unroll
    for (int off = 1; off <= 8; off <<= 1) mx = fmaxf(mx, __shfl_xor(mx, off));
    float e0 = expf(lg0 - mx), e1 = expf(lg1 - mx);
    float s = e0 + e1;
#pragma unroll
    for (int off = 1; off <= 8; off <<= 1) s += __shfl_xor(s, off);
    float inv = 1.0f / s;
    p0s += e0 * inv;
    p1s += e1 * inv;
  }
  p0s += __shfl_xor(p0s, 16); p0s += __shfl_xor(p0s, 32);
  p1s += __shfl_xor(p1s, 16); p1s += __shfl_xor(p1s, 32);
  __shared__ float sacc[4][21];
  __shared__ unsigned int sdone;
  if (quad == 0) sacc[w][l16] = p0s;
  if (quad == 1 && l16 < 5) sacc[w][16 + l16] = p1s;
  __syncthreads();
  if (tid < 21) {
    float s = sacc[0][tid] + sacc[1][tid] + sacc[2][tid] + sacc[3][tid];
    atomicAdd(&acc[b * 21 + tid], s);
  }
  __syncthreads();   // barrier drains vmcnt: this block's atomics are globally performed
  if (tid == 0) {
    __threadfence();
    sdone = atomicAdd(ctr, 1u);
  }
  __syncthreads();
  if (sdone == 63u && tid < 16) {
    float v[20];
    float mx = -1e30f;
#pragma unroll
    for (int c = 0; c < 20; ++c) {
      v[c] = atomicAdd(&acc[tid * 21 + c], 0.0f);   // coherent read (XCD-safe)
      mx = fmaxf(mx, v[c]);
    }
    float s = 0.0f;
#pragma unroll
    for (int c = 0; c < 20; ++c) { v[c] = expf(v[c] - mx); s += v[c]; }
    float inv = 1.0f / s;
#pragma unroll
    for (int c = 0; c < 20; ++c) out[tid * 20 + c] = v[c] * inv;
  }
}

extern "C" void kernel_launch(void* const* d_in, const int* in_sizes, int n_in,
                              void* d_out, int out_size, void* d_ws, size_t ws_size,
                              hipStream_t stream) {
  const int*   tids = (const int*)d_in[0];
  const float* TF   = (const float*)d_in[1];
  const float* DF   = (const float*)d_in[2];
  const float* emb  = (const float*)d_in[3];
  const float* fcW  = (const float*)d_in[4];
  const float* fcb  = (const float*)d_in[5];
  // d_in[6]=weiW, d_in[7]=weib: dead code (cw branch is provably all-ones)
  float* out = (float*)d_out;
  float* ws  = (float*)d_ws;
  unsigned short* xh   = (unsigned short*)(ws + OFF_XH);
  unsigned short* xT   = (unsigned short*)(ws + OFF_XT);
  unsigned short* vc   = (unsigned short*)(ws + OFF_VC);
  unsigned short* fcWb = (unsigned short*)(ws + OFF_FCWB);
  float* sq    = ws + OFF_SQ;
  float* part  = ws + OFF_PART;
  float* acc   = ws + OFF_ACC;
  unsigned int* ctr = (unsigned int*)(ws + OFF_CTR);

  k12_fused<<<384, 512, 0, stream>>>(tids, TF, DF, emb, xh, xT, sq, part,
                                     fcW, fcWb, acc, ctr);
  k45_fused<<<1536, 256, 0, stream>>>(xh, xT, tids, sq, part, vc);
  k5b6_lgts<<<64, 256, 0, stream>>>(vc, fcWb, fcb, acc, ctr, out);
}